// Round 1
// baseline (2196.031 us; speedup 1.0000x reference)
//
#include <hip/hip_runtime.h>
#include <cstdint>
#include <cstddef>

#define H_DIM 4096
#define DFF_DIM 16384
#define NROWS 4096  // B*S = 2*2048

typedef unsigned short bf16_t;
typedef __attribute__((ext_vector_type(8))) short bf16x8;
typedef __attribute__((ext_vector_type(4))) float f32x4;
typedef __attribute__((ext_vector_type(4))) unsigned short u16x4;

static __device__ __forceinline__ bf16_t f2bf(float f) {
  union { float f; unsigned int i; } v; v.f = f;
  unsigned int x = v.i;
  return (bf16_t)((x + 0x7fffu + ((x >> 16) & 1u)) >> 16);  // RNE
}

// global -> LDS direct async copy, 16B per lane. LDS dest must be linear in
// lane order (wave-uniform base + lane*16).
#define GLDS16(gp, lp)                                                    \
  __builtin_amdgcn_global_load_lds(                                       \
      (__attribute__((address_space(1))) void*)(gp),                      \
      (__attribute__((address_space(3))) void*)(lp), 16, 0, 0)

// ---------------------------------------------------------------------------
// Kernel 1: ln_in = input + residual + bias; LN(ln_in, gamma, beta) -> bf16
// One block per row of H=4096. 256 threads, 16 elems each via float4.
// ---------------------------------------------------------------------------
__global__ __launch_bounds__(256) void fused_ln_kernel(
    const float* __restrict__ inp, const float* __restrict__ res,
    const float* __restrict__ bias, const float* __restrict__ gamma,
    const float* __restrict__ beta, bf16_t* __restrict__ out) {
  int row = blockIdx.x;
  int t = threadIdx.x;
  const float4* pin = (const float4*)(inp + (size_t)row * H_DIM);
  const float4* pre = (const float4*)(res + (size_t)row * H_DIM);
  const float4* pbi = (const float4*)bias;
  float4 xv[4];
  float s = 0.f, ss = 0.f;
#pragma unroll
  for (int i = 0; i < 4; ++i) {
    int idx = t + i * 256;
    float4 a = pin[idx];
    float4 b = pre[idx];
    float4 c = pbi[idx];
    float4 v;
    v.x = a.x + b.x + c.x;
    v.y = a.y + b.y + c.y;
    v.z = a.z + b.z + c.z;
    v.w = a.w + b.w + c.w;
    xv[i] = v;
    s += v.x + v.y + v.z + v.w;
    ss += v.x * v.x + v.y * v.y + v.z * v.z + v.w * v.w;
  }
#pragma unroll
  for (int off = 32; off > 0; off >>= 1) {
    s += __shfl_xor(s, off);
    ss += __shfl_xor(ss, off);
  }
  __shared__ float sred[8];
  int w = t >> 6, l = t & 63;
  if (l == 0) { sred[w] = s; sred[4 + w] = ss; }
  __syncthreads();
  s = sred[0] + sred[1] + sred[2] + sred[3];
  ss = sred[4] + sred[5] + sred[6] + sred[7];
  const float inv = 1.f / (float)H_DIM;
  float mean = s * inv;
  float var = ss * inv - mean * mean;
  float rstd = rsqrtf(var + 1e-5f);
  const float4* pg = (const float4*)gamma;
  const float4* pb = (const float4*)beta;
#pragma unroll
  for (int i = 0; i < 4; ++i) {
    int idx = t + i * 256;
    float4 g = pg[idx];
    float4 bb = pb[idx];
    float4 v = xv[i];
    u16x4 o;
    o.x = f2bf((v.x - mean) * rstd * g.x + bb.x);
    o.y = f2bf((v.y - mean) * rstd * g.y + bb.y);
    o.z = f2bf((v.z - mean) * rstd * g.z + bb.z);
    o.w = f2bf((v.w - mean) * rstd * g.w + bb.w);
    *(u16x4*)(out + (size_t)row * H_DIM + (size_t)idx * 4) = o;
  }
}

// ---------------------------------------------------------------------------
// Kernel 2: W fp32 [K,N] -> Wt bf16 [N,K] (transpose + convert).
// 64x64 tiles via padded LDS; both phases fully coalesced.
// ---------------------------------------------------------------------------
__global__ __launch_bounds__(256) void transpose_cvt_kernel(
    const float* __restrict__ W, bf16_t* __restrict__ Wt, int K, int N) {
  __shared__ float tile[64][65];
  int nb = N >> 6;
  int bk = blockIdx.x / nb;
  int bn = blockIdx.x - bk * nb;
  int t = threadIdx.x;
  int r = t >> 4;           // 0..15
  int c4 = (t & 15) << 2;   // 0,4,...,60
#pragma unroll
  for (int p = 0; p < 4; ++p) {
    int row = r + p * 16;
    float4 v = *(const float4*)(W + (size_t)(bk * 64 + row) * N + bn * 64 + c4);
    tile[row][c4 + 0] = v.x;
    tile[row][c4 + 1] = v.y;
    tile[row][c4 + 2] = v.z;
    tile[row][c4 + 3] = v.w;
  }
  __syncthreads();
#pragma unroll
  for (int p = 0; p < 4; ++p) {
    int nn = r + p * 16;
    u16x4 o;
    o.x = f2bf(tile[c4 + 0][nn]);
    o.y = f2bf(tile[c4 + 1][nn]);
    o.z = f2bf(tile[c4 + 2][nn]);
    o.w = f2bf(tile[c4 + 3][nn]);
    *(u16x4*)(Wt + (size_t)(bn * 64 + nn) * K + bk * 64 + c4) = o;
  }
}

// ---------------------------------------------------------------------------
// Kernel 3: C[M,N] = A[M,K] * Bt[N,K]^T, bf16 inputs, fp32 accumulate.
// 128x128 tile, BK=32, 4 waves (each 64x64 = 4x4 MFMA 16x16x32 frags).
// global_load_lds width-16 staging with chunk-XOR pre-swizzle; XCD swizzle.
// EPI 0: out_bf16 = gelu_tanh(C + eb1[n])
// EPI 1: out_f32  = C + eb1[n] + eb2[n] + add1[m,n] + add2[m,n]
// ---------------------------------------------------------------------------
template <int EPI>
__global__ __launch_bounds__(256) void gemm_bt_kernel(
    const bf16_t* __restrict__ A, const bf16_t* __restrict__ Bt,
    int M, int N, int K,
    const float* __restrict__ eb1, const float* __restrict__ eb2,
    const float* __restrict__ add1, const float* __restrict__ add2,
    bf16_t* __restrict__ outb, float* __restrict__ outf) {
  constexpr int BK = 32;
  __shared__ bf16_t As[128 * BK];
  __shared__ bf16_t Bs[128 * BK];

  int nwg = gridDim.x;
  int bid = blockIdx.x;
  int wg = bid;
  if ((nwg & 7) == 0) wg = (bid & 7) * (nwg >> 3) + (bid >> 3);  // XCD swizzle
  int ntn = N >> 7;
  int tm = wg / ntn, tn = wg - tm * ntn;
  size_t m0 = (size_t)tm << 7, n0 = (size_t)tn << 7;

  int t = threadIdx.x;
  int l = t & 63;
  int w = t >> 6;
  int wr = w >> 1, wc = w & 1;

  f32x4 acc[4][4];
#pragma unroll
  for (int i = 0; i < 4; ++i)
#pragma unroll
    for (int j = 0; j < 4; ++j) acc[i][j] = {0.f, 0.f, 0.f, 0.f};

  // Staging geometry: tile = 128 rows x 32 bf16 = 8KB = 512 x 16B chunks.
  // Thread t covers chunks t and t+256. chunk c: row=c>>2, slot=c&3.
  // Pre-swizzle: LDS slot s of row r holds global k-group (s ^ (r&3)).
  int c0 = t, c1 = t + 256;
  int r0 = c0 >> 2, s0 = (c0 & 3) ^ (r0 & 3);
  int r1 = c1 >> 2, s1 = (c1 & 3) ^ (r1 & 3);
  const bf16_t* gA0 = A + (m0 + r0) * (size_t)K + s0 * 8;
  const bf16_t* gA1 = A + (m0 + r1) * (size_t)K + s1 * 8;
  const bf16_t* gB0 = Bt + (n0 + r0) * (size_t)K + s0 * 8;
  const bf16_t* gB1 = Bt + (n0 + r1) * (size_t)K + s1 * 8;
  bf16_t* lA0 = As + c0 * 8;
  bf16_t* lA1 = As + c1 * 8;
  bf16_t* lB0 = Bs + c0 * 8;
  bf16_t* lB1 = Bs + c1 * 8;

  // Fragment read offsets: lane needs k-group (l>>4) of its row; that group
  // sits at slot (l>>4)^(row&3), row&3 == l&3.
  int xr = (((l >> 4) ^ (l & 3)) << 3);
  int ar[4], br[4];
#pragma unroll
  for (int i = 0; i < 4; ++i) {
    ar[i] = (wr * 64 + i * 16 + (l & 15)) * BK + xr;
    br[i] = (wc * 64 + i * 16 + (l & 15)) * BK + xr;
  }

  for (int k0 = 0; k0 < K; k0 += BK) {
    GLDS16(gA0 + k0, lA0);
    GLDS16(gA1 + k0, lA1);
    GLDS16(gB0 + k0, lB0);
    GLDS16(gB1 + k0, lB1);
    __syncthreads();  // drains vmcnt -> LDS tiles valid
    bf16x8 af[4], bfr[4];
#pragma unroll
    for (int i = 0; i < 4; ++i) af[i] = *(const bf16x8*)(const void*)(As + ar[i]);
#pragma unroll
    for (int i = 0; i < 4; ++i) bfr[i] = *(const bf16x8*)(const void*)(Bs + br[i]);
#pragma unroll
    for (int mi = 0; mi < 4; ++mi)
#pragma unroll
      for (int nj = 0; nj < 4; ++nj)
        acc[mi][nj] = __builtin_amdgcn_mfma_f32_16x16x32_bf16(
            af[mi], bfr[nj], acc[mi][nj], 0, 0, 0);
    __syncthreads();  // all reads done before next-iter staging overwrites
  }

  // Epilogue. C/D layout: col = lane&15, row = (lane>>4)*4 + reg.
  int mb = (int)m0 + wr * 64;
  int nb2 = (int)n0 + wc * 64;
  int lr = (l >> 4) * 4;
  int lc = l & 15;
#pragma unroll
  for (int mi = 0; mi < 4; ++mi) {
#pragma unroll
    for (int i = 0; i < 4; ++i) {
      int rrow = mb + mi * 16 + lr + i;
      size_t base = (size_t)rrow * N;
#pragma unroll
      for (int nj = 0; nj < 4; ++nj) {
        int col = nb2 + nj * 16 + lc;
        float v = acc[mi][nj][i];
        if (EPI == 0) {
          float x = v + eb1[col];
          float u = 0.7978845608028654f * (x + 0.044715f * x * x * x);
          float th = 1.f - 2.f / (__expf(2.f * u) + 1.f);  // tanh(u)
          outb[base + col] = f2bf(0.5f * x * (1.f + th));
        } else {
          outf[base + col] =
              v + eb1[col] + eb2[col] + add1[base + col] + add2[base + col];
        }
      }
    }
  }
}

// ---------------------------------------------------------------------------
extern "C" void kernel_launch(void* const* d_in, const int* in_sizes, int n_in,
                              void* d_out, int out_size, void* d_ws,
                              size_t ws_size, hipStream_t stream) {
  const float* input = (const float*)d_in[0];
  const float* residual = (const float*)d_in[1];
  // d_in[2] residual_norm: unused by this op
  const float* bias = (const float*)d_in[3];
  const float* attn_nw = (const float*)d_in[4];
  const float* attn_nb = (const float*)d_in[5];
  const float* inter_w = (const float*)d_in[6];   // [H, DFF]
  const float* inter_b = (const float*)d_in[7];   // [DFF]
  const float* output_w = (const float*)d_in[8];  // [DFF, H]
  const float* output_b = (const float*)d_in[9];  // [H]
  float* out = (float*)d_out;

  // Workspace layout (bf16):
  //   ln    [NROWS, H]     32 MB
  //   w1t   [DFF, H]      128 MB   (inter_w transposed)
  //   w2t   [H, DFF]      128 MB   (output_w transposed)
  //   inter [NROWS, DFF]  128 MB
  char* ws = (char*)d_ws;
  bf16_t* lnb = (bf16_t*)ws;
  bf16_t* w1t = (bf16_t*)(ws + (size_t)NROWS * H_DIM * 2);
  bf16_t* w2t = (bf16_t*)(ws + (size_t)NROWS * H_DIM * 2 +
                          (size_t)H_DIM * DFF_DIM * 2);
  bf16_t* inter = (bf16_t*)(ws + (size_t)NROWS * H_DIM * 2 +
                            2 * (size_t)H_DIM * DFF_DIM * 2);

  fused_ln_kernel<<<NROWS, 256, 0, stream>>>(input, residual, bias, attn_nw,
                                             attn_nb, lnb);
  transpose_cvt_kernel<<<(H_DIM / 64) * (DFF_DIM / 64), 256, 0, stream>>>(
      inter_w, w1t, H_DIM, DFF_DIM);
  transpose_cvt_kernel<<<(DFF_DIM / 64) * (H_DIM / 64), 256, 0, stream>>>(
      output_w, w2t, DFF_DIM, H_DIM);
  gemm_bt_kernel<0><<<(NROWS / 128) * (DFF_DIM / 128), 256, 0, stream>>>(
      lnb, w1t, NROWS, DFF_DIM, H_DIM, inter_b, nullptr, nullptr, nullptr,
      inter, nullptr);
  gemm_bt_kernel<1><<<(NROWS / 128) * (H_DIM / 128), 256, 0, stream>>>(
      inter, w2t, NROWS, H_DIM, DFF_DIM, bias, output_b, residual, input,
      nullptr, out);
}

// Round 2
// 1473.757 us; speedup vs baseline: 1.4901x; 1.4901x over previous
//
#include <hip/hip_runtime.h>
#include <cstdint>
#include <cstddef>

#define H_DIM 4096
#define DFF_DIM 16384
#define NROWS 4096  // B*S = 2*2048

typedef unsigned short bf16_t;
typedef __attribute__((ext_vector_type(8))) short bf16x8;
typedef __attribute__((ext_vector_type(4))) float f32x4;
typedef __attribute__((ext_vector_type(4))) unsigned short u16x4;

static __device__ __forceinline__ bf16_t f2bf(float f) {
  union { float f; unsigned int i; } v; v.f = f;
  unsigned int x = v.i;
  return (bf16_t)((x + 0x7fffu + ((x >> 16) & 1u)) >> 16);  // RNE
}

// global -> LDS direct async copy, 16B per lane (wave-uniform base + lane*16).
#define GLDS16(gp, lp)                                                    \
  __builtin_amdgcn_global_load_lds(                                       \
      (__attribute__((address_space(1))) void*)(gp),                      \
      (__attribute__((address_space(3))) void*)(lp), 16, 0, 0)

// ---------------------------------------------------------------------------
// Kernel 1: ln_in = input + residual + bias; LN(ln_in, gamma, beta) -> bf16
// ---------------------------------------------------------------------------
__global__ __launch_bounds__(256) void fused_ln_kernel(
    const float* __restrict__ inp, const float* __restrict__ res,
    const float* __restrict__ bias, const float* __restrict__ gamma,
    const float* __restrict__ beta, bf16_t* __restrict__ out) {
  int row = blockIdx.x;
  int t = threadIdx.x;
  const float4* pin = (const float4*)(inp + (size_t)row * H_DIM);
  const float4* pre = (const float4*)(res + (size_t)row * H_DIM);
  const float4* pbi = (const float4*)bias;
  float4 xv[4];
  float s = 0.f, ss = 0.f;
#pragma unroll
  for (int i = 0; i < 4; ++i) {
    int idx = t + i * 256;
    float4 a = pin[idx];
    float4 b = pre[idx];
    float4 c = pbi[idx];
    float4 v;
    v.x = a.x + b.x + c.x;
    v.y = a.y + b.y + c.y;
    v.z = a.z + b.z + c.z;
    v.w = a.w + b.w + c.w;
    xv[i] = v;
    s += v.x + v.y + v.z + v.w;
    ss += v.x * v.x + v.y * v.y + v.z * v.z + v.w * v.w;
  }
#pragma unroll
  for (int off = 32; off > 0; off >>= 1) {
    s += __shfl_xor(s, off);
    ss += __shfl_xor(ss, off);
  }
  __shared__ float sred[8];
  int w = t >> 6, l = t & 63;
  if (l == 0) { sred[w] = s; sred[4 + w] = ss; }
  __syncthreads();
  s = sred[0] + sred[1] + sred[2] + sred[3];
  ss = sred[4] + sred[5] + sred[6] + sred[7];
  const float inv = 1.f / (float)H_DIM;
  float mean = s * inv;
  float var = ss * inv - mean * mean;
  float rstd = rsqrtf(var + 1e-5f);
  const float4* pg = (const float4*)gamma;
  const float4* pb = (const float4*)beta;
#pragma unroll
  for (int i = 0; i < 4; ++i) {
    int idx = t + i * 256;
    float4 g = pg[idx];
    float4 bb = pb[idx];
    float4 v = xv[i];
    u16x4 o;
    o.x = f2bf((v.x - mean) * rstd * g.x + bb.x);
    o.y = f2bf((v.y - mean) * rstd * g.y + bb.y);
    o.z = f2bf((v.z - mean) * rstd * g.z + bb.z);
    o.w = f2bf((v.w - mean) * rstd * g.w + bb.w);
    *(u16x4*)(out + (size_t)row * H_DIM + (size_t)idx * 4) = o;
  }
}

// ---------------------------------------------------------------------------
// Kernel 2: W fp32 [K,N] -> Wt bf16 [N,K] (transpose + convert).
// ---------------------------------------------------------------------------
__global__ __launch_bounds__(256) void transpose_cvt_kernel(
    const float* __restrict__ W, bf16_t* __restrict__ Wt, int K, int N) {
  __shared__ float tile[64][65];
  int nb = N >> 6;
  int bk = blockIdx.x / nb;
  int bn = blockIdx.x - bk * nb;
  int t = threadIdx.x;
  int r = t >> 4;
  int c4 = (t & 15) << 2;
#pragma unroll
  for (int p = 0; p < 4; ++p) {
    int row = r + p * 16;
    float4 v = *(const float4*)(W + (size_t)(bk * 64 + row) * N + bn * 64 + c4);
    tile[row][c4 + 0] = v.x;
    tile[row][c4 + 1] = v.y;
    tile[row][c4 + 2] = v.z;
    tile[row][c4 + 3] = v.w;
  }
  __syncthreads();
#pragma unroll
  for (int p = 0; p < 4; ++p) {
    int nn = r + p * 16;
    u16x4 o;
    o.x = f2bf(tile[c4 + 0][nn]);
    o.y = f2bf(tile[c4 + 1][nn]);
    o.z = f2bf(tile[c4 + 2][nn]);
    o.w = f2bf(tile[c4 + 3][nn]);
    *(u16x4*)(Wt + (size_t)(bn * 64 + nn) * K + bk * 64 + c4) = o;
  }
}

// ---------------------------------------------------------------------------
// Kernel 3: 256x256-tile 8-phase bf16 GEMM (C = A[M,K] * Bt[N,K]^T), fp32 acc.
// 512 threads = 8 waves (2M x 4N), per-wave 128x64 out = acc[8][4] frags.
// BK=64 per K-tile, double-buffered LDS (128 KB), half-tile (16KB) staging via
// global_load_lds w=16; XOR slot swizzle (kgrp ^= (row>>1)&3) applied on the
// GLOBAL source (LDS linear) and re-applied on ds_read -> conflict-free b128.
// Counted vmcnt(6) at phases 4/8 only; setprio(1) around MFMA clusters.
// EPI 0: out_bf16 = gelu_tanh(C + eb1[n])
// EPI 1: out_f32  = C + eb1[n] + eb2[n] + add1[m,n] + add2[m,n]
// ---------------------------------------------------------------------------
#define PHASE_TAIL(MIBASE)                                                  \
  __builtin_amdgcn_s_barrier();                                             \
  asm volatile("s_waitcnt lgkmcnt(0)" ::: "memory");                        \
  __builtin_amdgcn_s_setprio(1);                                            \
  _Pragma("unroll") for (int ii = 0; ii < 4; ++ii)                          \
      _Pragma("unroll") for (int jj = 0; jj < 4; ++jj) acc[MIBASE + ii][jj] = \
      __builtin_amdgcn_mfma_f32_16x16x32_bf16(aF[ii], bF[jj],               \
                                              acc[MIBASE + ii][jj], 0, 0, 0); \
  __builtin_amdgcn_s_setprio(0);                                            \
  __builtin_amdgcn_s_barrier();

template <int EPI>
__global__ __launch_bounds__(512, 2) void gemm8p_kernel(
    const bf16_t* __restrict__ A, const bf16_t* __restrict__ Bt,
    int M, int N, int K,
    const float* __restrict__ eb1, const float* __restrict__ eb2,
    const float* __restrict__ add1, const float* __restrict__ add2,
    bf16_t* __restrict__ outb, float* __restrict__ outf) {
  __shared__ char lds[131072];  // A: 2 x 32KB @0, B: 2 x 32KB @65536

  const int t = threadIdx.x;
  const int l = t & 63;
  const int wid = t >> 6;
  const int wr = wid >> 2;  // 0..1
  const int wc = wid & 3;   // 0..3

  // Block -> tile: XCD chunk swizzle, then 2-wide tn bands, tm-major (ntm=16).
  int nwg = gridDim.x;
  int bid = blockIdx.x;
  int wg = (bid & 7) * (nwg >> 3) + (bid >> 3);
  int band = wg >> 5;
  int r5 = wg & 31;
  int tn = band * 2 + (r5 & 1);
  int tm = r5 >> 1;
  size_t m0 = (size_t)tm * 256, n0 = (size_t)tn * 256;

  f32x4 acc[8][4];
#pragma unroll
  for (int i = 0; i < 8; ++i)
#pragma unroll
    for (int j = 0; j < 4; ++j) acc[i][j] = {0.f, 0.f, 0.f, 0.f};

  // Staging: half-tile = 256 rows x 32 k (16KB) = 1024 chunks of 16B.
  // Thread t covers chunks t and t+512 (LDS linear). Source k-slot pre-XORed.
  const int c0 = t, c1 = t + 512;
  const int row0 = c0 >> 2, row1 = c1 >> 2;
  const int ks0 = (c0 & 3) ^ ((row0 >> 1) & 3);
  const int ks1 = (c1 & 3) ^ ((row1 >> 1) & 3);
  const bf16_t* pA0 = A + (m0 + row0) * (size_t)K + ks0 * 8;
  const bf16_t* pA1 = A + (m0 + row1) * (size_t)K + ks1 * 8;
  const bf16_t* pB0 = Bt + (n0 + row0) * (size_t)K + ks0 * 8;
  const bf16_t* pB1 = Bt + (n0 + row1) * (size_t)K + ks1 * 8;

  auto stageA = [&](int b, int h, int T) {
    GLDS16(pA0 + (size_t)T * 64 + h * 32, lds + b * 32768 + h * 16384 + c0 * 16);
    GLDS16(pA1 + (size_t)T * 64 + h * 32, lds + b * 32768 + h * 16384 + c1 * 16);
  };
  auto stageB = [&](int b, int h, int T) {
    GLDS16(pB0 + (size_t)T * 64 + h * 32,
           lds + 65536 + b * 32768 + h * 16384 + c0 * 16);
    GLDS16(pB1 + (size_t)T * 64 + h * 32,
           lds + 65536 + b * 32768 + h * 16384 + c1 * 16);
  };

  // ds_read offsets: lane reads row=(base+(l&15)), k-octet (l>>4); physical
  // slot = (l>>4) ^ ((row>>1)&3) = (l>>4) ^ ((l>>1)&3)  (bases are 16-aligned).
  const int slot = (((l >> 4) ^ ((l >> 1) & 3)) << 4);
  int aoffs[8], boffs[4];
#pragma unroll
  for (int mi = 0; mi < 8; ++mi)
    aoffs[mi] = (wr * 128 + mi * 16 + (l & 15)) * 64 + slot;
#pragma unroll
  for (int nj = 0; nj < 4; ++nj)
    boffs[nj] = 65536 + (wc * 64 + nj * 16 + (l & 15)) * 64 + slot;

  auto rd8 = [&](int off) -> bf16x8 {
    return *(const bf16x8*)(const void*)(lds + off);
  };

  const int NT = K >> 6;   // K-tiles of 64
  const int NI = NT >> 1;  // 2 K-tiles per iteration

  // Prologue: tile0 (4 halves) -> buf0; tile1 {B-H0, A-H0, B-H1} -> buf1.
  stageA(0, 0, 0);
  stageB(0, 0, 0);
  stageA(0, 1, 0);
  stageB(0, 1, 0);
  asm volatile("s_waitcnt vmcnt(4)" ::: "memory");
  stageB(1, 0, 1);
  stageA(1, 0, 1);
  stageB(1, 1, 1);
  asm volatile("s_waitcnt vmcnt(6)" ::: "memory");
  __builtin_amdgcn_s_barrier();

  for (int it = 0; it < NI; ++it) {
    int T1 = 2 * it + 1;
    int Ta = 2 * it + 2; if (Ta >= NT) Ta = NT - 1;  // clamped (dead writes)
    int Tb = 2 * it + 3; if (Tb >= NT) Tb = NT - 1;
    bf16x8 aF[4], bF[4];
    // P1: buf0 kk0 — B nj0-3 + A mi0-3; stage buf1.A-H1 <- tile T1
#pragma unroll
    for (int j = 0; j < 4; ++j) bF[j] = rd8(boffs[j]);
#pragma unroll
    for (int i2 = 0; i2 < 4; ++i2) aF[i2] = rd8(aoffs[i2]);
    stageA(1, 1, T1);
    PHASE_TAIL(0)
    // P2: buf0 kk0 — A mi4-7; stage buf0.B-H0 <- Ta
#pragma unroll
    for (int i2 = 0; i2 < 4; ++i2) aF[i2] = rd8(aoffs[4 + i2]);
    stageB(0, 0, Ta);
    PHASE_TAIL(4)
    // P3: buf0 kk1 — B + A mi0-3; stage buf0.A-H0 <- Ta
#pragma unroll
    for (int j = 0; j < 4; ++j) bF[j] = rd8(boffs[j] + 16384);
#pragma unroll
    for (int i2 = 0; i2 < 4; ++i2) aF[i2] = rd8(aoffs[i2] + 16384);
    stageA(0, 0, Ta);
    PHASE_TAIL(0)
    // P4: buf0 kk1 — A mi4-7; stage buf0.B-H1 <- Ta; counted vmcnt
#pragma unroll
    for (int i2 = 0; i2 < 4; ++i2) aF[i2] = rd8(aoffs[4 + i2] + 16384);
    stageB(0, 1, Ta);
    asm volatile("s_waitcnt vmcnt(6)" ::: "memory");
    PHASE_TAIL(4)
    // P5: buf1 kk0 — B + A mi0-3; stage buf0.A-H1 <- Ta
#pragma unroll
    for (int j = 0; j < 4; ++j) bF[j] = rd8(boffs[j] + 32768);
#pragma unroll
    for (int i2 = 0; i2 < 4; ++i2) aF[i2] = rd8(aoffs[i2] + 32768);
    stageA(0, 1, Ta);
    PHASE_TAIL(0)
    // P6: buf1 kk0 — A mi4-7; stage buf1.B-H0 <- Tb
#pragma unroll
    for (int i2 = 0; i2 < 4; ++i2) aF[i2] = rd8(aoffs[4 + i2] + 32768);
    stageB(1, 0, Tb);
    PHASE_TAIL(4)
    // P7: buf1 kk1 — B + A mi0-3; stage buf1.A-H0 <- Tb
#pragma unroll
    for (int j = 0; j < 4; ++j) bF[j] = rd8(boffs[j] + 32768 + 16384);
#pragma unroll
    for (int i2 = 0; i2 < 4; ++i2) aF[i2] = rd8(aoffs[i2] + 32768 + 16384);
    stageA(1, 0, Tb);
    PHASE_TAIL(0)
    // P8: buf1 kk1 — A mi4-7; stage buf1.B-H1 <- Tb; counted vmcnt
#pragma unroll
    for (int i2 = 0; i2 < 4; ++i2) aF[i2] = rd8(aoffs[4 + i2] + 32768 + 16384);
    stageB(1, 1, Tb);
    asm volatile("s_waitcnt vmcnt(6)" ::: "memory");
    PHASE_TAIL(4)
  }
  asm volatile("s_waitcnt vmcnt(0)" ::: "memory");

  // Epilogue. C/D: col = lane&15, row = (lane>>4)*4 + reg.
  int mb = (int)m0 + wr * 128;
  int nb2 = (int)n0 + wc * 64;
  int lr = (l >> 4) * 4;
  int lc = l & 15;
#pragma unroll
  for (int mi = 0; mi < 8; ++mi) {
#pragma unroll
    for (int i2 = 0; i2 < 4; ++i2) {
      int rrow = mb + mi * 16 + lr + i2;
      size_t base = (size_t)rrow * N;
#pragma unroll
      for (int nj = 0; nj < 4; ++nj) {
        int col = nb2 + nj * 16 + lc;
        float v = acc[mi][nj][i2];
        if (EPI == 0) {
          float x = v + eb1[col];
          float u = 0.7978845608028654f * (x + 0.044715f * x * x * x);
          float th = 1.f - 2.f / (__expf(2.f * u) + 1.f);  // tanh(u)
          outb[base + col] = f2bf(0.5f * x * (1.f + th));
        } else {
          outf[base + col] =
              v + eb1[col] + eb2[col] + add1[base + col] + add2[base + col];
        }
      }
    }
  }
}

// ---------------------------------------------------------------------------
extern "C" void kernel_launch(void* const* d_in, const int* in_sizes, int n_in,
                              void* d_out, int out_size, void* d_ws,
                              size_t ws_size, hipStream_t stream) {
  const float* input = (const float*)d_in[0];
  const float* residual = (const float*)d_in[1];
  const float* bias = (const float*)d_in[3];
  const float* attn_nw = (const float*)d_in[4];
  const float* attn_nb = (const float*)d_in[5];
  const float* inter_w = (const float*)d_in[6];   // [H, DFF]
  const float* inter_b = (const float*)d_in[7];   // [DFF]
  const float* output_w = (const float*)d_in[8];  // [DFF, H]
  const float* output_b = (const float*)d_in[9];  // [H]
  float* out = (float*)d_out;

  char* ws = (char*)d_ws;
  bf16_t* lnb = (bf16_t*)ws;
  bf16_t* w1t = (bf16_t*)(ws + (size_t)NROWS * H_DIM * 2);
  bf16_t* w2t = (bf16_t*)(ws + (size_t)NROWS * H_DIM * 2 +
                          (size_t)H_DIM * DFF_DIM * 2);
  bf16_t* inter = (bf16_t*)(ws + (size_t)NROWS * H_DIM * 2 +
                            2 * (size_t)H_DIM * DFF_DIM * 2);

  fused_ln_kernel<<<NROWS, 256, 0, stream>>>(input, residual, bias, attn_nw,
                                             attn_nb, lnb);
  transpose_cvt_kernel<<<(H_DIM / 64) * (DFF_DIM / 64), 256, 0, stream>>>(
      inter_w, w1t, H_DIM, DFF_DIM);
  transpose_cvt_kernel<<<(DFF_DIM / 64) * (H_DIM / 64), 256, 0, stream>>>(
      output_w, w2t, DFF_DIM, H_DIM);
  gemm8p_kernel<0><<<(NROWS / 256) * (DFF_DIM / 256), 512, 0, stream>>>(
      lnb, w1t, NROWS, DFF_DIM, H_DIM, inter_b, nullptr, nullptr, nullptr,
      inter, nullptr);
  gemm8p_kernel<1><<<(NROWS / 256) * (H_DIM / 256), 512, 0, stream>>>(
      inter, w2t, NROWS, H_DIM, DFF_DIM, bias, output_b, residual, input,
      nullptr, out);
}